// Round 1
// baseline (14088.492 us; speedup 1.0000x reference)
//
#include <hip/hip_runtime.h>

#define NB 128
#define NSTEP 27

typedef __attribute__((ext_vector_type(8))) short bf16x8;
typedef __attribute__((ext_vector_type(4))) float f32x4;

__device__ inline float sigmoidf_(float x) { return 1.0f / (1.0f + expf(-x)); }
__device__ inline float softplusf_(float x) { return x > 20.0f ? x : log1pf(expf(x)); }
__device__ inline unsigned short f2bf(float f) {
  union { float f; unsigned u; } v; v.f = f;
  unsigned u = v.u;
  u += 0x7fffu + ((u >> 16) & 1u);   // RNE; no NaNs expected in this net
  return (unsigned short)(u >> 16);
}

// ---------------- fp32 -> bf16 weight conversion (once per launch) ----------------
__global__ __launch_bounds__(256) void k_convert_bf16(const float* __restrict__ src,
                                                      unsigned short* __restrict__ dst, int n) {
  int i = blockIdx.x * 256 + threadIdx.x;
  int stride = gridDim.x * 256;
  for (; i < n; i += stride) dst[i] = f2bf(src[i]);
}

// ---------------- psix1 (3->16, s2 p1, 32->16) + psix2 (16->16, s2 p1, 16->8), fused per batch ----
__global__ __launch_bounds__(256) void k_psix(
    const float* __restrict__ cur_base, int cur_bstride,
    const float* __restrict__ w1, const float* __restrict__ b1,
    const float* __restrict__ w2, const float* __restrict__ b2,
    float* __restrict__ px, unsigned short* __restrict__ gi_bf) {
  __shared__ float px1[16 * 256];
  int b = blockIdx.x, tid = threadIdx.x;
  const float* in = cur_base + (long)b * cur_bstride;
  for (int i = 0; i < 16; ++i) {
    int idx = tid + i * 256;              // [0,4096): oc*256 + oy*16 + ox
    int oc = idx >> 8, rem = idx & 255;
    int oy = rem >> 4, ox = rem & 15;
    float acc = b1[oc];
    for (int ic = 0; ic < 3; ++ic) {
      const float* ip = in + ic * 1024;
      const float* wp = w1 + (oc * 3 + ic) * 9;
#pragma unroll
      for (int ky = 0; ky < 3; ++ky) {
        int iy = 2 * oy + ky - 1;
        if ((unsigned)iy >= 32u) continue;
#pragma unroll
        for (int kx = 0; kx < 3; ++kx) {
          int ix = 2 * ox + kx - 1;
          if ((unsigned)ix >= 32u) continue;
          acc += ip[iy * 32 + ix] * wp[ky * 3 + kx];
        }
      }
    }
    px1[idx] = fmaxf(acc, 0.0f);
  }
  __syncthreads();
  for (int i = 0; i < 4; ++i) {
    int idx = tid + i * 256;              // [0,1024): oc*64 + oy*8 + ox
    int oc = idx >> 6, rem = idx & 63;
    int oy = rem >> 3, ox = rem & 7;
    float acc = b2[oc];
    for (int ic = 0; ic < 16; ++ic) {
      const float* lp = px1 + ic * 256;
      const float* wp = w2 + (oc * 16 + ic) * 9;
#pragma unroll
      for (int ky = 0; ky < 3; ++ky) {
        int iy = 2 * oy + ky - 1;
        if ((unsigned)iy >= 16u) continue;
#pragma unroll
        for (int kx = 0; kx < 3; ++kx) {
          int ix = 2 * ox + kx - 1;
          if ((unsigned)ix >= 16u) continue;
          acc += lp[iy * 16 + ix] * wp[ky * 3 + kx];
        }
      }
    }
    float r = fmaxf(acc, 0.0f);
    px[b * 1024 + idx] = r;
    gi_bf[b * 3072 + idx] = f2bf(r);
  }
}

// ---------------- enc1 (concat(px,h) 32->32) + enc2 (32->64), s1 p1 on 8x8, fused per batch ------
__global__ __launch_bounds__(256) void k_enc12(
    const float* __restrict__ px, const float* __restrict__ h,
    const float* __restrict__ w1, const float* __restrict__ b1,
    const float* __restrict__ w2, const float* __restrict__ b2,
    float* __restrict__ e2out) {
  __shared__ float s_in[32 * 100];
  __shared__ float s_e1[32 * 100];
  int b = blockIdx.x, tid = threadIdx.x;
  for (int i = tid; i < 3200; i += 256) { s_in[i] = 0.f; s_e1[i] = 0.f; }
  __syncthreads();
  for (int i = tid; i < 2048; i += 256) {
    int ch = i >> 6, rem = i & 63;
    float v = (ch < 16) ? px[b * 1024 + i] : h[b * 1024 + (ch - 16) * 64 + rem];
    s_in[ch * 100 + ((rem >> 3) + 1) * 10 + (rem & 7) + 1] = v;
  }
  __syncthreads();
  for (int i = 0; i < 8; ++i) {
    int idx = tid + i * 256;              // [0,2048)
    int oc = idx >> 6, rem = idx & 63;
    int oy = rem >> 3, ox = rem & 7;
    float acc = b1[oc];
    for (int ic = 0; ic < 32; ++ic) {
      const float* lp = s_in + ic * 100 + oy * 10 + ox;
      const float* wp = w1 + (oc * 32 + ic) * 9;
#pragma unroll
      for (int ky = 0; ky < 3; ++ky)
#pragma unroll
        for (int kx = 0; kx < 3; ++kx)
          acc += lp[ky * 10 + kx] * wp[ky * 3 + kx];
    }
    s_e1[oc * 100 + (oy + 1) * 10 + (ox + 1)] = fmaxf(acc, 0.f);
  }
  __syncthreads();
  for (int i = 0; i < 16; ++i) {
    int idx = tid + i * 256;              // [0,4096)
    int oc = idx >> 6, rem = idx & 63;
    int oy = rem >> 3, ox = rem & 7;
    float acc = b2[oc];
    for (int ic = 0; ic < 32; ++ic) {
      const float* lp = s_e1 + ic * 100 + oy * 10 + ox;
      const float* wp = w2 + (oc * 32 + ic) * 9;
#pragma unroll
      for (int ky = 0; ky < 3; ++ky)
#pragma unroll
        for (int kx = 0; kx < 3; ++kx)
          acc += lp[ky * 10 + kx] * wp[ky * 3 + kx];
    }
    e2out[b * 4096 + idx] = fmaxf(acc, 0.f);
  }
}

// ---------------- encm + encv (64->64 each, s1 p1) + z = zm + softplus(.)*eps -------------------
__global__ __launch_bounds__(256) void k_mv(
    const float* __restrict__ e2, const float* __restrict__ eps_t,
    const float* __restrict__ wm, const float* __restrict__ bm,
    const float* __restrict__ wv, const float* __restrict__ bv,
    float* __restrict__ zm_out, float* __restrict__ zlv_out, float* __restrict__ z) {
  __shared__ float s[64 * 100];
  int b = blockIdx.x >> 3, g = blockIdx.x & 7, tid = threadIdx.x;
  for (int i = tid; i < 6400; i += 256) s[i] = 0.f;
  __syncthreads();
  for (int i = tid; i < 4096; i += 256) {
    int ch = i >> 6, rem = i & 63;
    s[ch * 100 + ((rem >> 3) + 1) * 10 + (rem & 7) + 1] = e2[b * 4096 + i];
  }
  __syncthreads();
  for (int i = 0; i < 2; ++i) {
    int idx = tid + i * 256;              // [0,512): ocl*64 + pos
    int ocl = idx >> 6, rem = idx & 63;
    int oc = g * 8 + ocl;
    int oy = rem >> 3, ox = rem & 7;
    float am = bm[oc], av = bv[oc];
    for (int ic = 0; ic < 64; ++ic) {
      const float* lp = s + ic * 100 + oy * 10 + ox;
      const float* wpm = wm + (oc * 64 + ic) * 9;
      const float* wpv = wv + (oc * 64 + ic) * 9;
#pragma unroll
      for (int ky = 0; ky < 3; ++ky)
#pragma unroll
        for (int kx = 0; kx < 3; ++kx) {
          float v = lp[ky * 10 + kx];
          am += v * wpm[ky * 3 + kx];
          av += v * wpv[ky * 3 + kx];
        }
    }
    int o = b * 4096 + oc * 64 + rem;
    float sp = softplusf_(av);
    zm_out[o] = am;
    zlv_out[o] = sp;
    z[o] = am + sp * eps_t[o];
  }
}

// ---------------- psiz (64->16, s1 p1) -----------------------------------------------------------
__global__ __launch_bounds__(256) void k_psiz(
    const float* __restrict__ z, const float* __restrict__ w, const float* __restrict__ bias,
    float* __restrict__ zpsi, unsigned short* __restrict__ gi_bf) {
  __shared__ float s[64 * 100];
  int b = blockIdx.x, tid = threadIdx.x;
  for (int i = tid; i < 6400; i += 256) s[i] = 0.f;
  __syncthreads();
  for (int i = tid; i < 4096; i += 256) {
    int ch = i >> 6, rem = i & 63;
    s[ch * 100 + ((rem >> 3) + 1) * 10 + (rem & 7) + 1] = z[b * 4096 + i];
  }
  __syncthreads();
  for (int i = 0; i < 4; ++i) {
    int idx = tid + i * 256;              // [0,1024)
    int oc = idx >> 6, rem = idx & 63;
    int oy = rem >> 3, ox = rem & 7;
    float acc = bias[oc];
    for (int ic = 0; ic < 64; ++ic) {
      const float* lp = s + ic * 100 + oy * 10 + ox;
      const float* wp = w + (oc * 64 + ic) * 9;
#pragma unroll
      for (int ky = 0; ky < 3; ++ky)
#pragma unroll
        for (int kx = 0; kx < 3; ++kx)
          acc += lp[ky * 10 + kx] * wp[ky * 3 + kx];
    }
    float r = fmaxf(acc, 0.f);
    zpsi[b * 1024 + idx] = r;
    gi_bf[b * 3072 + 1024 + idx] = f2bf(r);
  }
}

// ---------------- dec1: ConvT(32->32, k3 s2 p1), 8x8 -> 15x15, relu -----------------------------
__global__ __launch_bounds__(256) void k_dec1(
    const float* __restrict__ h, const float* __restrict__ zpsi,
    const float* __restrict__ w, const float* __restrict__ bias,
    float* __restrict__ d1) {
  __shared__ float s[2048];   // [32][8][8]: ch<16 = h, else zpsi
  int b = blockIdx.x, tid = threadIdx.x;
  for (int i = tid; i < 2048; i += 256)
    s[i] = (i < 1024) ? h[b * 1024 + i] : zpsi[b * 1024 + i - 1024];
  __syncthreads();
  for (int idx = tid; idx < 7200; idx += 256) {
    int oc = idx / 225, rem = idx % 225;
    int y = rem / 15, x = rem % 15;
    float acc = bias[oc];
#pragma unroll
    for (int ky = 0; ky < 3; ++ky) {
      int ty = y + 1 - ky;
      if (ty < 0 || (ty & 1)) continue;
      int iy = ty >> 1;
      if (iy >= 8) continue;
#pragma unroll
      for (int kx = 0; kx < 3; ++kx) {
        int tx = x + 1 - kx;
        if (tx < 0 || (tx & 1)) continue;
        int ix = tx >> 1;
        if (ix >= 8) continue;
        for (int ic = 0; ic < 32; ++ic)
          acc += s[ic * 64 + iy * 8 + ix] * w[((ic * 32 + oc) * 3 + ky) * 3 + kx];
      }
    }
    d1[b * 7200 + idx] = fmaxf(acc, 0.f);
  }
}

// ---------------- dec2: ConvT(32->3, k3 s2 p0 outpad1), 15x15 -> 32x32, sigmoid -> d_out[t] -----
__global__ __launch_bounds__(256) void k_dec2(
    const float* __restrict__ d1, const float* __restrict__ w, const float* __restrict__ bias,
    float* __restrict__ out_t) {
  __shared__ float s[7200];
  int b = blockIdx.x, tid = threadIdx.x;
  for (int i = tid; i < 7200; i += 256) s[i] = d1[b * 7200 + i];
  __syncthreads();
  for (int i = 0; i < 12; ++i) {
    int idx = tid + i * 256;              // [0,3072): oc*1024 + y*32 + x
    int oc = idx >> 10, rem = idx & 1023;
    int y = rem >> 5, x = rem & 31;
    float acc = bias[oc];
#pragma unroll
    for (int ky = 0; ky < 3; ++ky) {
      int ty = y - ky;
      if (ty < 0 || (ty & 1)) continue;
      int iy = ty >> 1;
      if (iy >= 15) continue;
#pragma unroll
      for (int kx = 0; kx < 3; ++kx) {
        int tx = x - kx;
        if (tx < 0 || (tx & 1)) continue;
        int ix = tx >> 1;
        if (ix >= 15) continue;
        for (int ic = 0; ic < 32; ++ic)
          acc += s[ic * 225 + iy * 15 + ix] * w[((ic * 3 + oc) * 3 + ky) * 3 + kx];
      }
    }
    out_t[(long)b * (NSTEP * 3072) + idx] = sigmoidf_(acc);
  }
}

// ---------------- pri (16->32, s1 p1, relu) — last step only ------------------------------------
__global__ __launch_bounds__(256) void k_pri(
    const float* __restrict__ h, const float* __restrict__ w, const float* __restrict__ bias,
    float* __restrict__ p) {
  __shared__ float s[16 * 100];
  int b = blockIdx.x, tid = threadIdx.x;
  for (int i = tid; i < 1600; i += 256) s[i] = 0.f;
  __syncthreads();
  for (int i = tid; i < 1024; i += 256) {
    int ch = i >> 6, rem = i & 63;
    s[ch * 100 + ((rem >> 3) + 1) * 10 + (rem & 7) + 1] = h[b * 1024 + i];
  }
  __syncthreads();
  for (int i = 0; i < 8; ++i) {
    int idx = tid + i * 256;              // [0,2048)
    int oc = idx >> 6, rem = idx & 63;
    int oy = rem >> 3, ox = rem & 7;
    float acc = bias[oc];
    for (int ic = 0; ic < 16; ++ic) {
      const float* lp = s + ic * 100 + oy * 10 + ox;
      const float* wp = w + (oc * 16 + ic) * 9;
#pragma unroll
      for (int ky = 0; ky < 3; ++ky)
#pragma unroll
        for (int kx = 0; kx < 3; ++kx)
          acc += lp[ky * 10 + kx] * wp[ky * 3 + kx];
    }
    p[b * 2048 + idx] = fmaxf(acc, 0.f);
  }
}

// ---------------- prim + priv (32->64 each) -> pm, plv=softplus — last step only ----------------
__global__ __launch_bounds__(256) void k_pp(
    const float* __restrict__ p,
    const float* __restrict__ wm, const float* __restrict__ bm,
    const float* __restrict__ wv, const float* __restrict__ bv,
    float* __restrict__ pm_out, float* __restrict__ plv_out) {
  __shared__ float s[32 * 100];
  int b = blockIdx.x >> 3, g = blockIdx.x & 7, tid = threadIdx.x;
  for (int i = tid; i < 3200; i += 256) s[i] = 0.f;
  __syncthreads();
  for (int i = tid; i < 2048; i += 256) {
    int ch = i >> 6, rem = i & 63;
    s[ch * 100 + ((rem >> 3) + 1) * 10 + (rem & 7) + 1] = p[b * 2048 + i];
  }
  __syncthreads();
  for (int i = 0; i < 2; ++i) {
    int idx = tid + i * 256;              // [0,512)
    int ocl = idx >> 6, rem = idx & 63;
    int oc = g * 8 + ocl;
    int oy = rem >> 3, ox = rem & 7;
    float am = bm[oc], av = bv[oc];
    for (int ic = 0; ic < 32; ++ic) {
      const float* lp = s + ic * 100 + oy * 10 + ox;
      const float* wpm = wm + (oc * 32 + ic) * 9;
      const float* wpv = wv + (oc * 32 + ic) * 9;
#pragma unroll
      for (int ky = 0; ky < 3; ++ky)
#pragma unroll
        for (int kx = 0; kx < 3; ++kx) {
          float v = lp[ky * 10 + kx];
          am += v * wpm[ky * 3 + kx];
          av += v * wpv[ky * 3 + kx];
        }
    }
    int o = b * 4096 + oc * 64 + rem;
    pm_out[o] = am;
    plv_out[o] = softplusf_(av);
  }
}

// ---------------- GRU GEMM: out[m,n] = sum_k A[m,k]*W[n,k] + bias[n], bf16 MFMA -----------------
// A: [128, lda] bf16 (gi buffer), W: [3072, K] bf16. grid (48, 8), 4 waves/block, 1 16x16 tile/wave.
__global__ __launch_bounds__(256) void k_gemm_mfma(
    const unsigned short* __restrict__ A, int lda,
    const unsigned short* __restrict__ W,
    const float* __restrict__ bias,
    float* __restrict__ out, int K) {
  int tid = threadIdx.x;
  int wv = tid >> 6, lane = tid & 63;
  int lm = lane & 15, q = lane >> 4;
  int m0 = blockIdx.y * 16;
  int n0 = (blockIdx.x * 4 + wv) * 16;
  const unsigned short* Ap = A + (long)(m0 + lm) * lda + q * 8;
  const unsigned short* Wp = W + (long)(n0 + lm) * K + q * 8;
  f32x4 acc = {};
#pragma unroll 4
  for (int k = 0; k < K; k += 32) {
    bf16x8 a = *(const bf16x8*)(Ap + k);
    bf16x8 b = *(const bf16x8*)(Wp + k);
    acc = __builtin_amdgcn_mfma_f32_16x16x32_bf16(a, b, acc, 0, 0, 0);
  }
#pragma unroll
  for (int r = 0; r < 4; ++r) {
    int m = m0 + q * 4 + r;
    int n = n0 + lm;
    out[m * 3072 + n] = acc[r] + bias[n];
  }
}

// ---------------- GRU gates: h <- (1-u)*ng + u*h (in place), also refresh bf16 h slice ----------
__global__ __launch_bounds__(256) void k_gates(
    const float* __restrict__ gih, const float* __restrict__ ghh,
    float* __restrict__ h, unsigned short* __restrict__ gi_bf) {
  int i = blockIdx.x * 256 + threadIdx.x;   // [0, 128*1024)
  int b = i >> 10, j = i & 1023;
  const float* gi = gih + b * 3072;
  const float* gh = ghh + b * 3072;
  float r = sigmoidf_(gi[j] + gh[j]);
  float u = sigmoidf_(gi[j + 1024] + gh[j + 1024]);
  float ng = tanhf(gi[j + 2048] + r * gh[j + 2048]);
  float hv = h[i];
  float hn = (1.f - u) * ng + u * hv;
  h[i] = hn;
  gi_bf[b * 3072 + 2048 + j] = f2bf(hn);
}

extern "C" void kernel_launch(void* const* d_in, const int* in_sizes, int n_in,
                              void* d_out, int out_size, void* d_ws, size_t ws_size,
                              hipStream_t stream) {
  const float* x       = (const float*)d_in[0];
  const float* eps     = (const float*)d_in[1];
  const float* psix1_w = (const float*)d_in[2];
  const float* psix1_b = (const float*)d_in[3];
  const float* psix2_w = (const float*)d_in[4];
  const float* psix2_b = (const float*)d_in[5];
  const float* psiz_w  = (const float*)d_in[6];
  const float* psiz_b  = (const float*)d_in[7];
  const float* enc1_w  = (const float*)d_in[8];
  const float* enc1_b  = (const float*)d_in[9];
  const float* enc2_w  = (const float*)d_in[10];
  const float* enc2_b  = (const float*)d_in[11];
  const float* encm_w  = (const float*)d_in[12];
  const float* encm_b  = (const float*)d_in[13];
  const float* encv_w  = (const float*)d_in[14];
  const float* encv_b  = (const float*)d_in[15];
  const float* pri_w   = (const float*)d_in[16];
  const float* pri_b   = (const float*)d_in[17];
  const float* prim_w  = (const float*)d_in[18];
  const float* prim_b  = (const float*)d_in[19];
  const float* priv_w  = (const float*)d_in[20];
  const float* priv_b  = (const float*)d_in[21];
  const float* dec1_w  = (const float*)d_in[22];
  const float* dec1_b  = (const float*)d_in[23];
  const float* dec2_w  = (const float*)d_in[24];
  const float* dec2_b  = (const float*)d_in[25];
  const float* gru_wi  = (const float*)d_in[26];
  const float* gru_wh  = (const float*)d_in[27];
  const float* gru_bi  = (const float*)d_in[28];
  const float* gru_bh  = (const float*)d_in[29];

  float* out = (float*)d_out;
  float* zm_out  = out + 10616832;          // 128*27*3072
  float* zlv_out = zm_out + 524288;
  float* pm_out  = zlv_out + 524288;
  float* plv_out = pm_out + 524288;

  float* ws   = (float*)d_ws;
  float* h    = ws;                  // 131072
  float* px   = h + 131072;          // 131072
  float* e2   = px + 131072;         // 524288
  float* z    = e2 + 524288;         // 524288
  float* zpsi = z + 524288;          // 131072
  float* d1   = zpsi + 131072;       // 921600
  float* gih  = d1 + 921600;         // 393216
  float* ghh  = gih + 393216;        // 393216
  float* p    = ghh + 393216;        // 262144
  unsigned short* gi_bf = (unsigned short*)(p + 262144);     // 128*3072 bf16
  unsigned short* wi_bf = gi_bf + 393216;                    // 3072*3072 bf16
  unsigned short* wh_bf = wi_bf + 9437184;                   // 3072*1024 bf16

  hipMemsetAsync(h, 0, 131072 * sizeof(float), stream);
  hipMemsetAsync(gi_bf, 0, 393216 * sizeof(unsigned short), stream);
  k_convert_bf16<<<2048, 256, 0, stream>>>(gru_wi, wi_bf, 9437184);
  k_convert_bf16<<<1024, 256, 0, stream>>>(gru_wh, wh_bf, 3145728);

  dim3 ggrid(48, 8);
  for (int t = 0; t < NSTEP; ++t) {
    const float* cur_base;
    int cur_stride;
    if (t < 6) { cur_base = x + (long)t * 3072; cur_stride = 28 * 3072; }
    else       { cur_base = out + (long)(t - 1) * 3072; cur_stride = NSTEP * 3072; }

    k_psix<<<NB, 256, 0, stream>>>(cur_base, cur_stride, psix1_w, psix1_b, psix2_w, psix2_b, px, gi_bf);
    k_enc12<<<NB, 256, 0, stream>>>(px, h, enc1_w, enc1_b, enc2_w, enc2_b, e2);
    k_mv<<<NB * 8, 256, 0, stream>>>(e2, eps + (long)t * 524288, encm_w, encm_b, encv_w, encv_b,
                                     zm_out, zlv_out, z);
    k_psiz<<<NB, 256, 0, stream>>>(z, psiz_w, psiz_b, zpsi, gi_bf);
    k_dec1<<<NB, 256, 0, stream>>>(h, zpsi, dec1_w, dec1_b, d1);
    k_dec2<<<NB, 256, 0, stream>>>(d1, dec2_w, dec2_b, out + (long)t * 3072);

    if (t < NSTEP - 1) {
      k_gemm_mfma<<<ggrid, 256, 0, stream>>>(gi_bf, 3072, wi_bf, gru_bi, gih, 3072);
      k_gemm_mfma<<<ggrid, 256, 0, stream>>>(gi_bf + 2048, 3072, wh_bf, gru_bh, ghh, 1024);
      k_gates<<<512, 256, 0, stream>>>(gih, ghh, h, gi_bf);
    } else {
      k_pri<<<NB, 256, 0, stream>>>(h, pri_w, pri_b, p);
      k_pp<<<NB * 8, 256, 0, stream>>>(p, prim_w, prim_b, priv_w, priv_b, pm_out, plv_out);
    }
  }
}

// Round 2
// 4863.616 us; speedup vs baseline: 2.8967x; 2.8967x over previous
//
#include <hip/hip_runtime.h>

#define NSTEP 27

typedef _Float16 f16;
typedef __attribute__((ext_vector_type(8))) _Float16 f16x8;
typedef __attribute__((ext_vector_type(4))) float f32x4;

__device__ __forceinline__ float sigmoidf_(float x) { return 1.0f / (1.0f + expf(-x)); }
__device__ __forceinline__ float softplusf_(float x) { return x > 20.0f ? x : log1pf(expf(x)); }

// ---------------- workspace arena (f16 element offsets) ----------------
constexpr long OFF_WI   = 0;
constexpr long OFF_WH   = OFF_WI   + 3072L * 3072;
constexpr long OFF_WPX1 = OFF_WH   + 3072L * 1024;
constexpr long OFF_WPX2 = OFF_WPX1 + 16L * 32;
constexpr long OFF_WE1  = OFF_WPX2 + 16L * 160;
constexpr long OFF_WE2  = OFF_WE1  + 32L * 288;
constexpr long OFF_WMV  = OFF_WE2  + 64L * 288;
constexpr long OFF_WPZ  = OFF_WMV  + 128L * 576;
constexpr long OFF_WPRI = OFF_WPZ  + 16L * 576;
constexpr long OFF_WPMV = OFF_WPRI + 32L * 160;
constexpr long OFF_WD1  = OFF_WPMV + 128L * 288;
constexpr long OFF_A    = OFF_WD1  + 32L * 288;     // memset-zero region starts here
constexpr long OFF_APX1 = OFF_A;                    // [32768][32]
constexpr long OFF_APX2 = OFF_APX1 + 32768L * 32;   // [8192][160]
constexpr long OFF_AE1  = OFF_APX2 + 8192L * 160;   // [8192][288]
constexpr long OFF_AE2  = OFF_AE1  + 8192L * 288;   // [8192][288]
constexpr long OFF_AMV  = OFF_AE2  + 8192L * 288;   // [8192][576]
constexpr long OFF_APZ  = OFF_AMV  + 8192L * 576;   // [8192][576]
constexpr long OFF_AD1  = OFF_APZ  + 8192L * 576;   // 4 classes, total 8192*288
constexpr long OFF_D1F  = OFF_AD1  + 8192L * 288;   // d1 fmap f16 [128][32][225]
constexpr long OFF_APRI = OFF_D1F  + 128L * 7200;   // [8192][160]
constexpr long OFF_AP   = OFF_APRI + 8192L * 160;   // [8192][288]
constexpr long OFF_GI   = OFF_AP   + 8192L * 288;   // [128][3072]
constexpr long OFF_F16_END = OFF_GI + 128L * 3072;

// ---------------- MFMA 16x16x32 f16 core: C[m,n] = sum_k A[m,k]*B[n,k] ----------------
__device__ __forceinline__ f32x4 mma16(const f16* __restrict__ A, int lda,
                                       const f16* __restrict__ B, int ldb,
                                       int K, int lm, int q) {
  f32x4 acc = {};
  const f16* Ap = A + (long)lm * lda + q * 8;
  const f16* Bp = B + (long)lm * ldb + q * 8;
#pragma unroll 4
  for (int k = 0; k < K; k += 32) {
    f16x8 a = *(const f16x8*)(Ap + k);
    f16x8 b = *(const f16x8*)(Bp + k);
    acc = __builtin_amdgcn_mfma_f32_16x16x32_f16(a, b, acc, 0, 0, 0);
  }
  return acc;
}

// scatter value of fmap[ic][py][px] (8x8) into s1p1-conv im2col A (row stride ldk)
__device__ __forceinline__ void scat8(f16* __restrict__ A, int ldk, int b, int pos, int ic, float val) {
  int py = pos >> 3, px = pos & 7;
  f16 v = (f16)val;
  long row0 = (long)(b << 6);
#pragma unroll
  for (int ky = 0; ky < 3; ++ky) {
    int oy = py + 1 - ky;
    if ((unsigned)oy >= 8u) continue;
#pragma unroll
    for (int kx = 0; kx < 3; ++kx) {
      int ox = px + 1 - kx;
      if ((unsigned)ox >= 8u) continue;
      A[(row0 + oy * 8 + ox) * ldk + ic * 9 + ky * 3 + kx] = v;
    }
  }
}

// scatter fmap[ic][py][px] (8x8) into dec1 (ConvT 8->15, s2 p1) class-im2col
__device__ __forceinline__ void scatd1(f16* __restrict__ Ad1, int b, int pos, int ic, float val) {
  const long aoff[4] = {0, 262144, 786432, 1310720};
  const int Kc[4] = {32, 64, 64, 128};
  int py = pos >> 3, px = pos & 7;
  f16 v = (f16)val;
#pragma unroll
  for (int ky = 0; ky < 3; ++ky) {
    int y = 2 * py + ky - 1;
    if ((unsigned)y >= 15u) continue;
    int cy = y & 1;
    int nky = cy ? 2 : 1;           // y even -> single tap ky=1 ; y odd -> ky in {0,2}
    int tiy = cy ? (ky >> 1) : 0;
#pragma unroll
    for (int kx = 0; kx < 3; ++kx) {
      int x = 2 * px + kx - 1;
      if ((unsigned)x >= 15u) continue;
      int cx = x & 1;
      int nkx = cx ? 2 : 1;
      int tix = cx ? (kx >> 1) : 0;
      int c = cy * 2 + cx;
      int ntap = nky * nkx;
      Ad1[aoff[c] + (long)((b << 6) + ((y >> 1) << 3) + (x >> 1)) * Kc[c] + ic * ntap + tiy * nkx + tix] = v;
    }
  }
}

// ---------------- setup: weight fp32 -> f16 packing ----------------
__global__ __launch_bounds__(256) void k_wpack(const float* __restrict__ src, f16* __restrict__ dst,
                                               int N, int Ks, int Kd) {
  int tot = N * Kd, stride = gridDim.x * 256;
  for (int i = blockIdx.x * 256 + threadIdx.x; i < tot; i += stride) {
    int n = i / Kd, k = i - n * Kd;
    dst[i] = (k < Ks) ? (f16)src[n * Ks + k] : (f16)0.f;
  }
}

// dec1 ConvT weight -> per-class B [32][K_c]
__global__ __launch_bounds__(256) void k_wd1(const float* __restrict__ src, f16* __restrict__ dst) {
  int i = blockIdx.x * 256 + threadIdx.x;
  if (i >= 9216) return;
  int c, base;
  if (i < 1024) { c = 0; base = 0; }
  else if (i < 3072) { c = 1; base = 1024; }
  else if (i < 5120) { c = 2; base = 3072; }
  else { c = 3; base = 5120; }
  const int Kc[4] = {32, 64, 64, 128};
  int j = i - base, K = Kc[c];
  int oc = j / K, k = j - oc * K;
  int cy = c >> 1, cx = c & 1;
  int nky = cy ? 2 : 1, nkx = cx ? 2 : 1, ntap = nky * nkx;
  int ic = k / ntap, tap = k - ic * ntap;
  int tiy = tap / nkx, tix = tap - tiy * nkx;
  int ky = (nky == 1) ? 1 : tiy * 2;
  int kx = (nkx == 1) ? 1 : tix * 2;
  dst[i] = (f16)src[((ic * 32 + oc) * 3 + ky) * 3 + kx];
}

// ---------------- im2col of teacher-forced frame (t<6): 32x32 -> psix1 A ----------------
__global__ __launch_bounds__(256) void k_im2col_x(const float* __restrict__ xt, f16* __restrict__ Apx1) {
  int m = blockIdx.x * 256 + threadIdx.x;   // 32768
  int b = m >> 8, p = m & 255, oy = p >> 4, ox = p & 15;
  const float* src = xt + (long)b * 86016;  // 28*3072 batch stride
  f16* row = Apx1 + (long)m * 32;
#pragma unroll
  for (int ic = 0; ic < 3; ++ic)
#pragma unroll
    for (int ky = 0; ky < 3; ++ky) {
      int y = 2 * oy + ky - 1;
      if ((unsigned)y >= 32u) continue;
#pragma unroll
      for (int kx = 0; kx < 3; ++kx) {
        int x = 2 * ox + kx - 1;
        if ((unsigned)x >= 32u) continue;
        row[ic * 9 + ky * 3 + kx] = (f16)src[ic * 1024 + y * 32 + x];
      }
    }
}

// ---------------- im2col of h (t=26 only, for pri) ----------------
__global__ __launch_bounds__(256) void k_im2col_h(const float* __restrict__ h, f16* __restrict__ Apri) {
  int m = blockIdx.x * 256 + threadIdx.x;   // 8192
  int b = m >> 6, p = m & 63, py = p >> 3, px = p & 7;
  f16* row = Apri + (long)m * 160;
#pragma unroll
  for (int ic = 0; ic < 16; ++ic)
#pragma unroll
    for (int ky = 0; ky < 3; ++ky)
#pragma unroll
      for (int kx = 0; kx < 3; ++kx) {
        int y = py + ky - 1, x = px + kx - 1;
        float v = ((unsigned)y < 8u && (unsigned)x < 8u) ? h[(long)b * 1024 + ic * 64 + y * 8 + x] : 0.f;
        row[ic * 9 + ky * 3 + kx] = (f16)v;
      }
}

// ---------------- psix1 GEMM: M=32768, N=16, K=32; epilogue relu + stride-2 scatter to psix2 A --
__global__ __launch_bounds__(256) void k_g_px1(const f16* __restrict__ A, const f16* __restrict__ B,
                                               const float* __restrict__ bias, f16* __restrict__ Apx2) {
  int tid = threadIdx.x, wv = tid >> 6, lane = tid & 63, lm = lane & 15, q = lane >> 4;
  int m0 = (blockIdx.x * 4 + wv) * 16;
  f32x4 acc = mma16(A + (long)m0 * 32, 32, B, 32, 32, lm, q);
  float bb = bias[lm];
#pragma unroll
  for (int r = 0; r < 4; ++r) {
    int m = m0 + q * 4 + r;
    float val = fmaxf(acc[r] + bb, 0.f);
    int b = m >> 8, p = m & 255, y = p >> 4, x = p & 15;
    f16 v = (f16)val;
#pragma unroll
    for (int ky = 0; ky < 3; ++ky) {
      int ty = y + 1 - ky;
      if (ty < 0 || (ty & 1)) continue;
      int oy = ty >> 1; if (oy >= 8) continue;
#pragma unroll
      for (int kx = 0; kx < 3; ++kx) {
        int tx = x + 1 - kx;
        if (tx < 0 || (tx & 1)) continue;
        int ox = tx >> 1; if (ox >= 8) continue;
        Apx2[(long)((b << 6) + oy * 8 + ox) * 160 + lm * 9 + ky * 3 + kx] = v;
      }
    }
  }
}

// ---------------- psix2 GEMM: M=8192, N=16, K=160; relu -> gi slice + scatter enc1 A ------------
__global__ __launch_bounds__(256) void k_g_px2(const f16* __restrict__ A, const f16* __restrict__ B,
                                               const float* __restrict__ bias,
                                               f16* __restrict__ gi, f16* __restrict__ Ae1) {
  int tid = threadIdx.x, wv = tid >> 6, lane = tid & 63, lm = lane & 15, q = lane >> 4;
  int m0 = (blockIdx.x * 4 + wv) * 16;
  f32x4 acc = mma16(A + (long)m0 * 160, 160, B, 160, 160, lm, q);
  float bb = bias[lm];
#pragma unroll
  for (int r = 0; r < 4; ++r) {
    int m = m0 + q * 4 + r;
    float val = fmaxf(acc[r] + bb, 0.f);
    int b = m >> 6, p = m & 63;
    gi[(long)b * 3072 + lm * 64 + p] = (f16)val;
    scat8(Ae1, 288, b, p, lm, val);
  }
}

// ---------------- generic conv GEMM: relu + scatter to next im2col -----------------------------
__global__ __launch_bounds__(256) void k_g_conv(const f16* __restrict__ A, int K,
                                                const f16* __restrict__ B, const float* __restrict__ bias,
                                                f16* __restrict__ Adst, int ldk) {
  int tid = threadIdx.x, wv = tid >> 6, lane = tid & 63, lm = lane & 15, q = lane >> 4;
  int m0 = (blockIdx.x * 4 + wv) * 16, n0 = blockIdx.y * 16;
  f32x4 acc = mma16(A + (long)m0 * K, K, B + (long)n0 * K, K, K, lm, q);
  int n = n0 + lm;
  float bb = bias[n];
#pragma unroll
  for (int r = 0; r < 4; ++r) {
    int m = m0 + q * 4 + r;
    float val = fmaxf(acc[r] + bb, 0.f);
    scat8(Adst, ldk, m >> 6, m & 63, n, val);
  }
}

// ---------------- encm+encv dual GEMM: K=576, N=64; z = m + softplus(v)*eps -> psiz A ----------
__global__ __launch_bounds__(256) void k_g_mv(const f16* __restrict__ A,
                                              const f16* __restrict__ Bm, const f16* __restrict__ Bv,
                                              const float* __restrict__ bm, const float* __restrict__ bv,
                                              const float* __restrict__ eps_t, f16* __restrict__ Apz,
                                              float* __restrict__ zm, float* __restrict__ zlv, int last) {
  int tid = threadIdx.x, wv = tid >> 6, lane = tid & 63, lm = lane & 15, q = lane >> 4;
  int m0 = (blockIdx.x * 4 + wv) * 16, n0 = blockIdx.y * 16;
  f32x4 am = {}, av = {};
  const f16* Ap = A + (long)(m0 + lm) * 576 + q * 8;
  const f16* Bmp = Bm + (long)(n0 + lm) * 576 + q * 8;
  const f16* Bvp = Bv + (long)(n0 + lm) * 576 + q * 8;
#pragma unroll 3
  for (int k = 0; k < 576; k += 32) {
    f16x8 a = *(const f16x8*)(Ap + k);
    am = __builtin_amdgcn_mfma_f32_16x16x32_f16(a, *(const f16x8*)(Bmp + k), am, 0, 0, 0);
    av = __builtin_amdgcn_mfma_f32_16x16x32_f16(a, *(const f16x8*)(Bvp + k), av, 0, 0, 0);
  }
  int n = n0 + lm;
  float bbm = bm[n], bbv = bv[n];
#pragma unroll
  for (int r = 0; r < 4; ++r) {
    int m = m0 + q * 4 + r;
    int b = m >> 6, p = m & 63;
    float zmv = am[r] + bbm;
    float sp = softplusf_(av[r] + bbv);
    float z = zmv + sp * eps_t[(long)b * 4096 + n * 64 + p];
    scat8(Apz, 576, b, p, n, z);
    if (last) {
      zm[(long)b * 4096 + n * 64 + p] = zmv;
      zlv[(long)b * 4096 + n * 64 + p] = sp;
    }
  }
}

// ---------------- psiz GEMM: K=576, N=16; relu -> gi slice + dec1 class-im2col (ic 16..31) ------
__global__ __launch_bounds__(256) void k_g_pz(const f16* __restrict__ A, const f16* __restrict__ B,
                                              const float* __restrict__ bias,
                                              f16* __restrict__ gi, f16* __restrict__ Ad1) {
  int tid = threadIdx.x, wv = tid >> 6, lane = tid & 63, lm = lane & 15, q = lane >> 4;
  int m0 = (blockIdx.x * 4 + wv) * 16;
  f32x4 acc = mma16(A + (long)m0 * 576, 576, B, 576, 576, lm, q);
  float bb = bias[lm];
#pragma unroll
  for (int r = 0; r < 4; ++r) {
    int m = m0 + q * 4 + r;
    float val = fmaxf(acc[r] + bb, 0.f);
    int b = m >> 6, p = m & 63;
    gi[(long)b * 3072 + 1024 + lm * 64 + p] = (f16)val;
    scatd1(Ad1, b, p, 16 + lm, val);
  }
}

// ---------------- dec1 class GEMM: ConvT 8->15, relu -> d1 fmap f16 ----------------------------
__global__ __launch_bounds__(256) void k_g_d1(const f16* __restrict__ Ad1, const f16* __restrict__ Bd1,
                                              const float* __restrict__ bias, f16* __restrict__ d1f) {
  const int Kc[4] = {32, 64, 64, 128};
  const long aoff[4] = {0, 262144, 786432, 1310720};
  const long boff[4] = {0, 1024, 3072, 5120};
  int c = blockIdx.z;
  int tid = threadIdx.x, wv = tid >> 6, lane = tid & 63, lm = lane & 15, q = lane >> 4;
  int m0 = (blockIdx.x * 4 + wv) * 16, n0 = blockIdx.y * 16;
  int K = Kc[c];
  f32x4 acc = mma16(Ad1 + aoff[c] + (long)m0 * K, K, Bd1 + boff[c] + (long)n0 * K, K, K, lm, q);
  int n = n0 + lm;
  float bb = bias[n];
  int cy = c >> 1, cx = c & 1;
#pragma unroll
  for (int r = 0; r < 4; ++r) {
    int m = m0 + q * 4 + r;
    int b = m >> 6, pos = m & 63;
    int iy = 2 * (pos >> 3) + cy, ix = 2 * (pos & 7) + cx;
    if (iy < 15 && ix < 15)
      d1f[(long)b * 7200 + n * 225 + iy * 15 + ix] = (f16)fmaxf(acc[r] + bb, 0.f);
  }
}

// ---------------- dec2 direct: ConvT 15->32 s2 p0 outpad1, sigmoid -> d_out + psix1 A ----------
__global__ __launch_bounds__(256) void k_dec2(const f16* __restrict__ d1f, const float* __restrict__ w,
                                              const float* __restrict__ bias,
                                              float* __restrict__ out_t, f16* __restrict__ Apx1) {
  __shared__ f16 s[7200];
  int b = blockIdx.x, tid = threadIdx.x;
  for (int i = tid; i < 7200; i += 256) s[i] = d1f[(long)b * 7200 + i];
  __syncthreads();
  int wvi = tid >> 6, lane = tid & 63;
  int cy = wvi >> 1, cx = wvi & 1;
  int lx = lane & 15, ly = lane >> 4;
  int x = 2 * lx + cx;
  float b0 = bias[0], b1 = bias[1], b2 = bias[2];
  float acc[4][3];
#pragma unroll
  for (int j = 0; j < 4; ++j) { acc[j][0] = b0; acc[j][1] = b1; acc[j][2] = b2; }
  int nky = cy ? 1 : 2, nkx = cx ? 1 : 2;
  for (int ic = 0; ic < 32; ++ic) {
    const f16* sp = s + ic * 225;
    const float* wic = w + ic * 27;
    for (int ty = 0; ty < nky; ++ty) {
      int ky = cy ? 1 : ty * 2;
      for (int tx = 0; tx < nkx; ++tx) {
        int kx = cx ? 1 : tx * 2;
        int ix = (x - kx) >> 1;
        bool xv = (unsigned)ix < 15u;
        float w0 = wic[ky * 3 + kx];
        float w1 = wic[9 + ky * 3 + kx];
        float w2 = wic[18 + ky * 3 + kx];
#pragma unroll
        for (int j = 0; j < 4; ++j) {
          int py = j * 4 + ly;
          int iy = (2 * py + cy - ky) >> 1;
          if (xv && (unsigned)iy < 15u) {
            float v = (float)sp[iy * 15 + ix];
            acc[j][0] += v * w0; acc[j][1] += v * w1; acc[j][2] += v * w2;
          }
        }
      }
    }
  }
#pragma unroll
  for (int j = 0; j < 4; ++j) {
    int py = j * 4 + ly;
    int y = 2 * py + cy;
#pragma unroll
    for (int oc = 0; oc < 3; ++oc) {
      float sg = 1.0f / (1.0f + expf(-acc[j][oc]));
      out_t[(long)b * 82944 + oc * 1024 + y * 32 + x] = sg;
      f16 v = (f16)sg;
#pragma unroll
      for (int ky = 0; ky < 3; ++ky) {
        int ty = y + 1 - ky;
        if (ty < 0 || (ty & 1)) continue;
        int oy = ty >> 1; if (oy >= 16) continue;
#pragma unroll
        for (int kx = 0; kx < 3; ++kx) {
          int tx = x + 1 - kx;
          if (tx < 0 || (tx & 1)) continue;
          int ox = tx >> 1; if (ox >= 16) continue;
          Apx1[(long)((b << 8) + oy * 16 + ox) * 32 + oc * 9 + ky * 3 + kx] = v;
        }
      }
    }
  }
}

// ---------------- prim+priv dual GEMM: K=288, N=64 -> pm, plv (t=26 only) ----------------------
__global__ __launch_bounds__(256) void k_g_pmv(const f16* __restrict__ A,
                                               const f16* __restrict__ Bm, const f16* __restrict__ Bv,
                                               const float* __restrict__ bm, const float* __restrict__ bv,
                                               float* __restrict__ pm, float* __restrict__ plv) {
  int tid = threadIdx.x, wv = tid >> 6, lane = tid & 63, lm = lane & 15, q = lane >> 4;
  int m0 = (blockIdx.x * 4 + wv) * 16, n0 = blockIdx.y * 16;
  f32x4 am = {}, av = {};
  const f16* Ap = A + (long)(m0 + lm) * 288 + q * 8;
  const f16* Bmp = Bm + (long)(n0 + lm) * 288 + q * 8;
  const f16* Bvp = Bv + (long)(n0 + lm) * 288 + q * 8;
#pragma unroll 3
  for (int k = 0; k < 288; k += 32) {
    f16x8 a = *(const f16x8*)(Ap + k);
    am = __builtin_amdgcn_mfma_f32_16x16x32_f16(a, *(const f16x8*)(Bmp + k), am, 0, 0, 0);
    av = __builtin_amdgcn_mfma_f32_16x16x32_f16(a, *(const f16x8*)(Bvp + k), av, 0, 0, 0);
  }
  int n = n0 + lm;
  float bbm = bm[n], bbv = bv[n];
#pragma unroll
  for (int r = 0; r < 4; ++r) {
    int m = m0 + q * 4 + r;
    int b = m >> 6, p = m & 63;
    pm[(long)b * 4096 + n * 64 + p] = am[r] + bbm;
    plv[(long)b * 4096 + n * 64 + p] = softplusf_(av[r] + bbv);
  }
}

// ---------------- GRU GEMMs (z=0: wi K=3072; z=1: wh K=1024) -----------------------------------
__global__ __launch_bounds__(256) void k_g_gru(const f16* __restrict__ gi,
                                               const f16* __restrict__ wi, const f16* __restrict__ wh,
                                               const float* __restrict__ bi, const float* __restrict__ bh,
                                               float* __restrict__ gih, float* __restrict__ ghh) {
  int tid = threadIdx.x, wv = tid >> 6, lane = tid & 63, lm = lane & 15, q = lane >> 4;
  int z = blockIdx.z;
  const f16* A = z ? gi + 2048 : gi;
  const f16* B = z ? wh : wi;
  int K = z ? 1024 : 3072;
  const float* bias = z ? bh : bi;
  float* out = z ? ghh : gih;
  int m0 = blockIdx.y * 16;
  int n0 = (blockIdx.x * 4 + wv) * 16;
  f32x4 acc = {};
  const f16* Ap = A + (long)(m0 + lm) * 3072 + q * 8;
  const f16* Bp = B + (long)(n0 + lm) * K + q * 8;
#pragma unroll 4
  for (int k = 0; k < K; k += 32) {
    f16x8 a = *(const f16x8*)(Ap + k);
    f16x8 bfr = *(const f16x8*)(Bp + k);
    acc = __builtin_amdgcn_mfma_f32_16x16x32_f16(a, bfr, acc, 0, 0, 0);
  }
  int n = n0 + lm;
  float bb = bias[n];
#pragma unroll
  for (int r = 0; r < 4; ++r)
    out[(long)(m0 + q * 4 + r) * 3072 + n] = acc[r] + bb;
}

// ---------------- GRU gates: h update + gi h-slice + enc1A/dec1A h scatters --------------------
__global__ __launch_bounds__(256) void k_gates(const float* __restrict__ gih, const float* __restrict__ ghh,
                                               float* __restrict__ h, f16* __restrict__ gi,
                                               f16* __restrict__ Ae1, f16* __restrict__ Ad1) {
  int i = blockIdx.x * 256 + threadIdx.x;   // 131072
  int b = i >> 10, j = i & 1023;
  const float* gp = gih + (long)b * 3072;
  const float* hp = ghh + (long)b * 3072;
  float r = sigmoidf_(gp[j] + hp[j]);
  float u = sigmoidf_(gp[j + 1024] + hp[j + 1024]);
  float ng = tanhf(gp[j + 2048] + r * hp[j + 2048]);
  float hv = h[i];
  float hn = (1.f - u) * ng + u * hv;
  h[i] = hn;
  gi[(long)b * 3072 + 2048 + j] = (f16)hn;
  int ch = j >> 6, pos = j & 63;
  scat8(Ae1, 288, b, pos, 16 + ch, hn);
  scatd1(Ad1, b, pos, ch, hn);
}

extern "C" void kernel_launch(void* const* d_in, const int* in_sizes, int n_in,
                              void* d_out, int out_size, void* d_ws, size_t ws_size,
                              hipStream_t stream) {
  const float* x       = (const float*)d_in[0];
  const float* eps     = (const float*)d_in[1];
  const float* psix1_w = (const float*)d_in[2];
  const float* psix1_b = (const float*)d_in[3];
  const float* psix2_w = (const float*)d_in[4];
  const float* psix2_b = (const float*)d_in[5];
  const float* psiz_w  = (const float*)d_in[6];
  const float* psiz_b  = (const float*)d_in[7];
  const float* enc1_w  = (const float*)d_in[8];
  const float* enc1_b  = (const float*)d_in[9];
  const float* enc2_w  = (const float*)d_in[10];
  const float* enc2_b  = (const float*)d_in[11];
  const float* encm_w  = (const float*)d_in[12];
  const float* encm_b  = (const float*)d_in[13];
  const float* encv_w  = (const float*)d_in[14];
  const float* encv_b  = (const float*)d_in[15];
  const float* pri_w   = (const float*)d_in[16];
  const float* pri_b   = (const float*)d_in[17];
  const float* prim_w  = (const float*)d_in[18];
  const float* prim_b  = (const float*)d_in[19];
  const float* priv_w  = (const float*)d_in[20];
  const float* priv_b  = (const float*)d_in[21];
  const float* dec1_w  = (const float*)d_in[22];
  const float* dec1_b  = (const float*)d_in[23];
  const float* dec2_w  = (const float*)d_in[24];
  const float* dec2_b  = (const float*)d_in[25];
  const float* gru_wi  = (const float*)d_in[26];
  const float* gru_wh  = (const float*)d_in[27];
  const float* gru_bi  = (const float*)d_in[28];
  const float* gru_bh  = (const float*)d_in[29];

  float* out = (float*)d_out;
  float* zm_out  = out + 10616832;          // 128*27*3072
  float* zlv_out = zm_out + 524288;
  float* pm_out  = zlv_out + 524288;
  float* plv_out = pm_out + 524288;

  f16* ws16 = (f16*)d_ws;
  f16* wi_f  = ws16 + OFF_WI;
  f16* wh_f  = ws16 + OFF_WH;
  f16* w_px1 = ws16 + OFF_WPX1;
  f16* w_px2 = ws16 + OFF_WPX2;
  f16* w_e1  = ws16 + OFF_WE1;
  f16* w_e2  = ws16 + OFF_WE2;
  f16* w_mv  = ws16 + OFF_WMV;
  f16* w_pz  = ws16 + OFF_WPZ;
  f16* w_pri = ws16 + OFF_WPRI;
  f16* w_pmv = ws16 + OFF_WPMV;
  f16* w_d1  = ws16 + OFF_WD1;
  f16* Apx1  = ws16 + OFF_APX1;
  f16* Apx2  = ws16 + OFF_APX2;
  f16* Ae1   = ws16 + OFF_AE1;
  f16* Ae2   = ws16 + OFF_AE2;
  f16* Amv   = ws16 + OFF_AMV;
  f16* Apz   = ws16 + OFF_APZ;
  f16* Ad1   = ws16 + OFF_AD1;
  f16* d1f   = ws16 + OFF_D1F;
  f16* Apri  = ws16 + OFF_APRI;
  f16* Ap    = ws16 + OFF_AP;
  f16* gi    = ws16 + OFF_GI;
  float* fws = (float*)(ws16 + OFF_F16_END);
  float* h   = fws;                  // 131072
  float* gih = h + 131072;           // 393216
  float* ghh = gih + 393216;         // 393216

  // zero the im2col arena (sets all pad/boundary slots + gi h-slice + h state)
  hipMemsetAsync(ws16 + OFF_A, 0, (size_t)(OFF_F16_END - OFF_A) * 2, stream);
  hipMemsetAsync(h, 0, 131072 * sizeof(float), stream);

  // weight packing (once per launch)
  k_wpack<<<2048, 256, 0, stream>>>(gru_wi, wi_f, 3072, 3072, 3072);
  k_wpack<<<1024, 256, 0, stream>>>(gru_wh, wh_f, 3072, 1024, 1024);
  k_wpack<<<2, 256, 0, stream>>>(psix1_w, w_px1, 16, 27, 32);
  k_wpack<<<10, 256, 0, stream>>>(psix2_w, w_px2, 16, 144, 160);
  k_wpack<<<36, 256, 0, stream>>>(enc1_w, w_e1, 32, 288, 288);
  k_wpack<<<72, 256, 0, stream>>>(enc2_w, w_e2, 64, 288, 288);
  k_wpack<<<144, 256, 0, stream>>>(encm_w, w_mv, 64, 576, 576);
  k_wpack<<<144, 256, 0, stream>>>(encv_w, w_mv + 64L * 576, 64, 576, 576);
  k_wpack<<<36, 256, 0, stream>>>(psiz_w, w_pz, 16, 576, 576);
  k_wpack<<<20, 256, 0, stream>>>(pri_w, w_pri, 32, 144, 160);
  k_wpack<<<72, 256, 0, stream>>>(prim_w, w_pmv, 64, 288, 288);
  k_wpack<<<72, 256, 0, stream>>>(priv_w, w_pmv + 64L * 288, 64, 288, 288);
  k_wd1<<<36, 256, 0, stream>>>(dec1_w, w_d1);

  for (int t = 0; t < NSTEP; ++t) {
    if (t < 6)
      k_im2col_x<<<128, 256, 0, stream>>>(x + (long)t * 3072, Apx1);

    k_g_px1<<<512, 256, 0, stream>>>(Apx1, w_px1, psix1_b, Apx2);
    k_g_px2<<<128, 256, 0, stream>>>(Apx2, w_px2, psix2_b, gi, Ae1);
    k_g_conv<<<dim3(128, 2), 256, 0, stream>>>(Ae1, 288, w_e1, enc1_b, Ae2, 288);
    k_g_conv<<<dim3(128, 4), 256, 0, stream>>>(Ae2, 288, w_e2, enc2_b, Amv, 576);
    k_g_mv<<<dim3(128, 4), 256, 0, stream>>>(Amv, w_mv, w_mv + 64L * 576, encm_b, encv_b,
                                             eps + (long)t * 524288, Apz, zm_out, zlv_out, t == NSTEP - 1);
    k_g_pz<<<128, 256, 0, stream>>>(Apz, w_pz, psiz_b, gi, Ad1);
    k_g_d1<<<dim3(128, 2, 4), 256, 0, stream>>>(Ad1, w_d1, dec1_b, d1f);
    k_dec2<<<128, 256, 0, stream>>>(d1f, dec2_w, dec2_b, out + (long)t * 3072, Apx1);

    if (t < NSTEP - 1) {
      k_g_gru<<<dim3(48, 8, 2), 256, 0, stream>>>(gi, wi_f, wh_f, gru_bi, gru_bh, gih, ghh);
      k_gates<<<512, 256, 0, stream>>>(gih, ghh, h, gi, Ae1, Ad1);
    } else {
      k_im2col_h<<<32, 256, 0, stream>>>(h, Apri);
      k_g_conv<<<dim3(128, 2), 256, 0, stream>>>(Apri, 160, w_pri, pri_b, Ap, 288);
      k_g_pmv<<<dim3(128, 4), 256, 0, stream>>>(Ap, w_pmv, w_pmv + 64L * 288, prim_b, priv_b, pm_out, plv_out);
    }
  }
}

// Round 3
// 3331.740 us; speedup vs baseline: 4.2286x; 1.4598x over previous
//
#include <hip/hip_runtime.h>

#define NSTEP 27

typedef _Float16 f16;
typedef __attribute__((ext_vector_type(8))) _Float16 f16x8;
typedef __attribute__((ext_vector_type(4))) float f32x4;

#define MFMA(a, b, c) __builtin_amdgcn_mfma_f32_16x16x32_f16(a, b, c, 0, 0, 0)

__device__ __forceinline__ float sigmoidf_(float x) { return 1.0f / (1.0f + expf(-x)); }
__device__ __forceinline__ float softplusf_(float x) { return x > 20.0f ? x : log1pf(expf(x)); }

// ---------------- f16 workspace arena ----------------
constexpr long OFF_WI   = 0;                         // [3072][3072]
constexpr long OFF_WH   = OFF_WI   + 3072L * 3072;   // [3072][1024]
constexpr long OFF_WPX1 = OFF_WH   + 3072L * 1024;   // [16][32]
constexpr long OFF_WPX2 = OFF_WPX1 + 512;            // [16][160]
constexpr long OFF_WE1  = OFF_WPX2 + 2560;           // [32][288]
constexpr long OFF_WE2  = OFF_WE1  + 9216;           // [64][288]
constexpr long OFF_WMV  = OFF_WE2  + 18432;          // [128][576]
constexpr long OFF_WPZ  = OFF_WMV  + 73728;          // [16][576]
constexpr long OFF_WPRI = OFF_WPZ  + 9216;           // [32][160]
constexpr long OFF_WPMV = OFF_WPRI + 5120;           // [128][288]
constexpr long OFF_WD1  = OFF_WPMV + 36864;          // [9216] 4 classes
constexpr long OFF_GI   = OFF_WD1  + 9216;           // [128][3072]
constexpr long OFF_F16_END = OFF_GI + 128L * 3072;

struct Params {
  const float* frame; long fstride;
  const float* eps_t;
  const f16 *wpx1, *wpx2, *we1, *we2, *wmv, *wpz, *wd1, *wpri, *wpmv;
  const float *bpx1, *bpx2, *be1, *be2, *bm, *bv, *bpz, *bd1;
  const float *d2w, *d2b, *bpri, *bpm, *bpv, *gbi, *gbh;
  const float *gih0, *gih1, *ghh;
  float* hG; f16* gi;
  float *out_t, *zm, *zlv, *pm, *plv;
  int t, last;
};

// scatter fmap value at (pos=py*8+px, ic) into 8x8 s1p1-conv im2col A (padded row stride ldk)
__device__ __forceinline__ void scat8_lds(f16* __restrict__ A, int ldk, int pos, int ic, float val) {
  int py = pos >> 3, px = pos & 7;
  f16 v = (f16)val;
#pragma unroll
  for (int ky = 0; ky < 3; ++ky) {
    int oy = py + 1 - ky;
    if ((unsigned)oy >= 8u) continue;
#pragma unroll
    for (int kx = 0; kx < 3; ++kx) {
      int ox = px + 1 - kx;
      if ((unsigned)ox >= 8u) continue;
      A[(oy * 8 + ox) * ldk + ic * 9 + ky * 3 + kx] = v;
    }
  }
}

// scatter fmap value into dec1 ConvT (8->15, s2 p1) parity-class im2col (padded strides)
__device__ __forceinline__ void scatd1_lds(f16* __restrict__ Ad1, int pos, int ic, float val) {
  const int aof[4] = {0, 2560, 7168, 11776};
  const int Kp[4] = {40, 72, 72, 136};
  int py = pos >> 3, px = pos & 7;
  f16 v = (f16)val;
#pragma unroll
  for (int ky = 0; ky < 3; ++ky) {
    int y = 2 * py + ky - 1;
    if ((unsigned)y >= 15u) continue;
    int cy = y & 1;
    int nky = cy ? 2 : 1;
    int tiy = cy ? (ky >> 1) : 0;
#pragma unroll
    for (int kx = 0; kx < 3; ++kx) {
      int x = 2 * px + kx - 1;
      if ((unsigned)x >= 15u) continue;
      int cx = x & 1;
      int nkx = cx ? 2 : 1;
      int tix = cx ? (kx >> 1) : 0;
      int c = cy * 2 + cx;
      Ad1[aof[c] + ((y >> 1) * 8 + (x >> 1)) * Kp[c] + ic * (nky * nkx) + tiy * nkx + tix] = v;
    }
  }
}

// ---------------- setup: weight fp32 -> f16 packing ----------------
__global__ __launch_bounds__(256) void k_wpack(const float* __restrict__ src, f16* __restrict__ dst,
                                               int N, int Ks, int Kd) {
  int tot = N * Kd, stride = gridDim.x * 256;
  for (int i = blockIdx.x * 256 + threadIdx.x; i < tot; i += stride) {
    int n = i / Kd, k = i - n * Kd;
    dst[i] = (k < Ks) ? (f16)src[n * Ks + k] : (f16)0.f;
  }
}

__global__ __launch_bounds__(256) void k_wd1(const float* __restrict__ src, f16* __restrict__ dst) {
  int i = blockIdx.x * 256 + threadIdx.x;
  if (i >= 9216) return;
  int c, base;
  if (i < 1024) { c = 0; base = 0; }
  else if (i < 3072) { c = 1; base = 1024; }
  else if (i < 5120) { c = 2; base = 3072; }
  else { c = 3; base = 5120; }
  const int Kc[4] = {32, 64, 64, 128};
  int j = i - base, K = Kc[c];
  int oc = j / K, k = j - oc * K;
  int cy = c >> 1, cx = c & 1;
  int nky = cy ? 2 : 1, nkx = cx ? 2 : 1, ntap = nky * nkx;
  int ic = k / ntap, tap = k - ic * ntap;
  int tiy = tap / nkx, tix = tap - tiy * nkx;
  int ky = (nky == 1) ? 1 : tiy * 2;
  int kx = (nkx == 1) ? 1 : tix * 2;
  dst[i] = (f16)src[((ic * 32 + oc) * 3 + ky) * 3 + kx];
}

// =================== fused per-batch step kernel ===================
// 1 block = 1 batch. LDS (f16 units, 16B-aligned, padded strides for bank-conflict-free b128):
//  hbuf [16][64] @0 | B1 [64][584] @1024 | B2 [64][296] @38400 | B3 @57344:
//  A1 [256][40] @B3, frame/A2 [64][168] @B3+10240; later Ad1 (20480) / Apri.
__global__ __launch_bounds__(256) void k_step(Params P) {
  __shared__ f16 lds[78336];
  f16* hbuf = lds;
  f16* B1 = lds + 1024;
  f16* B2 = lds + 38400;
  f16* B3 = lds + 57344;
  f16* A1 = B3;
  f16* frame = B3 + 10240;
  f16* A2 = B3 + 10240;

  int b = blockIdx.x, tid = threadIdx.x;
  int wv = tid >> 6, lane = tid & 63, lm = lane & 15, q = lane >> 4;
  f32x4 z4 = {};

  // ---- GRU gates of previous step -> h_t ----
  for (int i = tid; i < 1024; i += 256) {
    float hn = 0.f;
    if (P.t) {
      long o = (long)b * 3072 + i;
      float ir = P.gih0[o] + P.gih1[o] + P.gbi[i];
      float iz = P.gih0[o + 1024] + P.gih1[o + 1024] + P.gbi[i + 1024];
      float in_ = P.gih0[o + 2048] + P.gih1[o + 2048] + P.gbi[i + 2048];
      float hr = P.ghh[o] + P.gbh[i];
      float hz = P.ghh[o + 1024] + P.gbh[i + 1024];
      float hnn = P.ghh[o + 2048] + P.gbh[i + 2048];
      float r = sigmoidf_(ir + hr), u = sigmoidf_(iz + hz);
      float ng = tanhf(in_ + r * hnn);
      hn = (1.f - u) * ng + u * P.hG[b * 1024 + i];
    }
    P.hG[b * 1024 + i] = hn;
    hbuf[i] = (f16)hn;
    P.gi[(long)b * 3072 + 2048 + i] = (f16)hn;
  }
  // ---- stage input frame ----
  const float* fr = P.frame + (long)b * P.fstride;
  for (int i = tid; i < 3072; i += 256) frame[i] = (f16)fr[i];
  __syncthreads();
  // ---- build A1 (psix1 im2col, 32x32 s2 p1 -> 256 rows x K32) ----
  {
    int row = tid, oy = row >> 4, ox = row & 15;
    f16* rp = A1 + row * 40;
    int k = 0;
#pragma unroll
    for (int ic = 0; ic < 3; ++ic)
#pragma unroll
      for (int ky = 0; ky < 3; ++ky) {
        int y = 2 * oy + ky - 1;
#pragma unroll
        for (int kx = 0; kx < 3; ++kx, ++k) {
          int x = 2 * ox + kx - 1;
          rp[k] = ((unsigned)y < 32u && (unsigned)x < 32u) ? frame[ic * 1024 + y * 32 + x] : (f16)0;
        }
      }
    for (; k < 40; ++k) rp[k] = (f16)0;
  }
  __syncthreads();
  // ---- zero A2 (overlays dead frame), A3 (B2), B1 ----
  {
    int4 zz = {0, 0, 0, 0};
    for (int i = tid; i < 10752 / 8; i += 256) ((int4*)A2)[i] = zz;
    for (int i = tid; i < 18944 / 8; i += 256) ((int4*)B2)[i] = zz;
    for (int i = tid; i < 37376 / 8; i += 256) ((int4*)B1)[i] = zz;
  }
  __syncthreads();
  // ---- h -> enc1 im2col (ic 16..31) ----
  for (int i = tid; i < 1024; i += 256)
    scat8_lds(B2, 296, i & 63, 16 + (i >> 6), (float)hbuf[i]);
  // ---- psix1: M=256 (4 m-tiles/wave), N=16, K=32; relu -> stride-2 scatter to A2 ----
  {
    f16x8 bf = *(const f16x8*)(P.wpx1 + lm * 32 + q * 8);
    float bb = P.bpx1[lm];
#pragma unroll
    for (int mi = 0; mi < 4; ++mi) {
      int mt = wv * 4 + mi;
      f16x8 a = *(const f16x8*)(A1 + (mt * 16 + lm) * 40 + q * 8);
      f32x4 acc = MFMA(a, bf, z4);
#pragma unroll
      for (int r = 0; r < 4; ++r) {
        int m = mt * 16 + q * 4 + r;
        float val = fmaxf(acc[r] + bb, 0.f);
        int y = m >> 4, x = m & 15;
        f16 v = (f16)val;
#pragma unroll
        for (int ky = 0; ky < 3; ++ky) {
          int ty = y + 1 - ky;
          if (ty < 0 || (ty & 1)) continue;
          int oy = ty >> 1; if (oy >= 8) continue;
#pragma unroll
          for (int kx = 0; kx < 3; ++kx) {
            int tx = x + 1 - kx;
            if (tx < 0 || (tx & 1)) continue;
            int ox = tx >> 1; if (ox >= 8) continue;
            A2[(oy * 8 + ox) * 168 + lm * 9 + ky * 3 + kx] = v;
          }
        }
      }
    }
  }
  __syncthreads();
  // ---- psix2: M=64 (m-tile=wv), N=16, K=160; relu -> gi + enc1 im2col (ic 0..15) ----
  {
    f32x4 acc = {};
#pragma unroll
    for (int k = 0; k < 160; k += 32) {
      f16x8 a = *(const f16x8*)(A2 + (wv * 16 + lm) * 168 + k + q * 8);
      f16x8 bf = *(const f16x8*)(P.wpx2 + lm * 160 + k + q * 8);
      acc = MFMA(a, bf, acc);
    }
    float bb = P.bpx2[lm];
#pragma unroll
    for (int r = 0; r < 4; ++r) {
      int pos = wv * 16 + q * 4 + r;
      float val = fmaxf(acc[r] + bb, 0.f);
      P.gi[(long)b * 3072 + lm * 64 + pos] = (f16)val;
      scat8_lds(B2, 296, pos, lm, val);
    }
  }
  __syncthreads();
  // ---- enc1: M=64, N=32, K=288; in-place scatter back into B2; h -> Ad1 overlapped ----
  {
    int nt = wv & 1, mtb = (wv >> 1) * 2;
    f32x4 a0 = {}, a1 = {};
#pragma unroll
    for (int k = 0; k < 288; k += 32) {
      f16x8 bf = *(const f16x8*)(P.we1 + (nt * 16 + lm) * 288 + k + q * 8);
      f16x8 x0 = *(const f16x8*)(B2 + (mtb * 16 + lm) * 296 + k + q * 8);
      f16x8 x1 = *(const f16x8*)(B2 + ((mtb + 1) * 16 + lm) * 296 + k + q * 8);
      a0 = MFMA(x0, bf, a0);
      a1 = MFMA(x1, bf, a1);
    }
    for (int i = tid; i < 1024; i += 256)      // h -> dec1 class-im2col (ic 0..15), B3 now free
      scatd1_lds(B3, i & 63, i >> 6, (float)hbuf[i]);
    __syncthreads();
    float bb = P.be1[nt * 16 + lm];
#pragma unroll
    for (int r = 0; r < 4; ++r) {
      scat8_lds(B2, 296, mtb * 16 + q * 4 + r, nt * 16 + lm, fmaxf(a0[r] + bb, 0.f));
      scat8_lds(B2, 296, (mtb + 1) * 16 + q * 4 + r, nt * 16 + lm, fmaxf(a1[r] + bb, 0.f));
    }
  }
  __syncthreads();
  // ---- enc2: M=64, N=64 (n-tile=wv), K=288; -> Amv (B1) ----
  {
    f32x4 acc[4] = {};
#pragma unroll
    for (int k = 0; k < 288; k += 32) {
      f16x8 bf = *(const f16x8*)(P.we2 + (wv * 16 + lm) * 288 + k + q * 8);
#pragma unroll
      for (int mt = 0; mt < 4; ++mt) {
        f16x8 a = *(const f16x8*)(B2 + (mt * 16 + lm) * 296 + k + q * 8);
        acc[mt] = MFMA(a, bf, acc[mt]);
      }
    }
    int ch = wv * 16 + lm;
    float bb = P.be2[ch];
#pragma unroll
    for (int mt = 0; mt < 4; ++mt)
#pragma unroll
      for (int r = 0; r < 4; ++r)
        scat8_lds(B1, 584, mt * 16 + q * 4 + r, ch, fmaxf(acc[mt][r] + bb, 0.f));
  }
  __syncthreads();
  // ---- encm+encv dual: M=64, K=576; z = zm + softplus(zv)*eps, in-place -> Apz (B1) ----
  {
    f32x4 am[4] = {}, av[4] = {};
    int ch = wv * 16 + lm;
#pragma unroll 2
    for (int k = 0; k < 576; k += 32) {
      f16x8 bm = *(const f16x8*)(P.wmv + (long)ch * 576 + k + q * 8);
      f16x8 bv = *(const f16x8*)(P.wmv + (long)(64 + ch) * 576 + k + q * 8);
#pragma unroll
      for (int mt = 0; mt < 4; ++mt) {
        f16x8 a = *(const f16x8*)(B1 + (mt * 16 + lm) * 584 + k + q * 8);
        am[mt] = MFMA(a, bm, am[mt]);
        av[mt] = MFMA(a, bv, av[mt]);
      }
    }
    __syncthreads();
    float bbm = P.bm[ch], bbv = P.bv[ch];
#pragma unroll
    for (int mt = 0; mt < 4; ++mt)
#pragma unroll
      for (int r = 0; r < 4; ++r) {
        int pos = mt * 16 + q * 4 + r;
        float zmv = am[mt][r] + bbm;
        float sp = softplusf_(av[mt][r] + bbv);
        float zval = zmv + sp * P.eps_t[(long)b * 4096 + ch * 64 + pos];
        if (P.last) {
          P.zm[(long)b * 4096 + ch * 64 + pos] = zmv;
          P.zlv[(long)b * 4096 + ch * 64 + pos] = sp;
        }
        scat8_lds(B1, 584, pos, ch, zval);
      }
  }
  __syncthreads();
  // ---- psiz: M=64 (m-tile=wv), N=16, K=576; relu -> gi + dec1 class-im2col (ic 16..31) ----
  {
    f32x4 acc = {};
#pragma unroll 2
    for (int k = 0; k < 576; k += 32) {
      f16x8 a = *(const f16x8*)(B1 + (wv * 16 + lm) * 584 + k + q * 8);
      f16x8 bf = *(const f16x8*)(P.wpz + (long)lm * 576 + k + q * 8);
      acc = MFMA(a, bf, acc);
    }
    float bb = P.bpz[lm];
#pragma unroll
    for (int r = 0; r < 4; ++r) {
      int pos = wv * 16 + q * 4 + r;
      float val = fmaxf(acc[r] + bb, 0.f);
      P.gi[(long)b * 3072 + 1024 + lm * 64 + pos] = (f16)val;
      scatd1_lds(B3, pos, 16 + lm, val);
    }
  }
  __syncthreads();
  // ---- dec1 ConvT via 4 parity-class GEMMs: M=64 (m-tile=wv), N=32 -> d1f (B2, stride 240) ----
  {
    const int Kc[4] = {32, 64, 64, 128};
    const int Kp[4] = {40, 72, 72, 136};
    const int aof[4] = {0, 2560, 7168, 11776};
    const int bof[4] = {0, 1024, 3072, 5120};
#pragma unroll
    for (int c = 0; c < 4; ++c) {
      int cy = c >> 1, cx = c & 1;
#pragma unroll
      for (int nt = 0; nt < 2; ++nt) {
        f32x4 acc = {};
        for (int k = 0; k < Kc[c]; k += 32) {
          f16x8 a = *(const f16x8*)(B3 + aof[c] + (wv * 16 + lm) * Kp[c] + k + q * 8);
          f16x8 bf = *(const f16x8*)(P.wd1 + bof[c] + (nt * 16 + lm) * Kc[c] + k + q * 8);
          acc = MFMA(a, bf, acc);
        }
        int oc = nt * 16 + lm;
        float bb = P.bd1[oc];
#pragma unroll
        for (int r = 0; r < 4; ++r) {
          int m = wv * 16 + q * 4 + r;
          int y = 2 * (m >> 3) + cy, x = 2 * (m & 7) + cx;
          if (y < 15 && x < 15)
            B2[oc * 240 + y * 15 + x] = (f16)fmaxf(acc[r] + bb, 0.f);
        }
      }
    }
  }
  __syncthreads();
  // ---- dec2 ConvT 15->32 (direct, parity per wave), sigmoid -> out ----
  {
    int cy2 = wv >> 1, cx2 = wv & 1;
    int lx = lane & 15, ly = lane >> 4;
    int x = 2 * lx + cx2;
    float b0 = P.d2b[0], b1 = P.d2b[1], b2 = P.d2b[2];
    float acc[4][3];
#pragma unroll
    for (int j = 0; j < 4; ++j) { acc[j][0] = b0; acc[j][1] = b1; acc[j][2] = b2; }
    int nky = cy2 ? 1 : 2, nkx = cx2 ? 1 : 2;
    for (int ic = 0; ic < 32; ++ic) {
      const f16* sp = B2 + ic * 240;
      const float* wic = P.d2w + ic * 27;
      for (int ty = 0; ty < nky; ++ty) {
        int ky = cy2 ? 1 : ty * 2;
        for (int tx = 0; tx < nkx; ++tx) {
          int kx = cx2 ? 1 : tx * 2;
          int ix = (x - kx) >> 1;
          bool xv = (unsigned)ix < 15u;
          float w0 = wic[ky * 3 + kx];
          float w1 = wic[9 + ky * 3 + kx];
          float w2 = wic[18 + ky * 3 + kx];
#pragma unroll
          for (int j = 0; j < 4; ++j) {
            int py = j * 4 + ly;
            int iy = (2 * py + cy2 - ky) >> 1;
            if (xv && (unsigned)iy < 15u) {
              float v = (float)sp[iy * 15 + ix];
              acc[j][0] += v * w0; acc[j][1] += v * w1; acc[j][2] += v * w2;
            }
          }
        }
      }
    }
#pragma unroll
    for (int j = 0; j < 4; ++j) {
      int y = 2 * (j * 4 + ly) + cy2;
#pragma unroll
      for (int oc = 0; oc < 3; ++oc)
        P.out_t[(long)b * 82944 + oc * 1024 + y * 32 + x] = sigmoidf_(acc[j][oc]);
    }
  }
  // ---- last step only: pri -> prim/priv ----
  if (P.last) {
    if (tid < 64) {                 // Apri im2col of h in B3 [64][168]
      int py = tid >> 3, px = tid & 7;
      f16* rp = B3 + tid * 168;
      int k = 0;
      for (int ic = 0; ic < 16; ++ic)
        for (int ky = 0; ky < 3; ++ky) {
          int y = py + ky - 1;
          for (int kx = 0; kx < 3; ++kx, ++k) {
            int x = px + kx - 1;
            rp[k] = ((unsigned)y < 8u && (unsigned)x < 8u) ? hbuf[ic * 64 + y * 8 + x] : (f16)0;
          }
        }
      for (; k < 168; ++k) rp[k] = (f16)0;
    }
    {
      int4 zz = {0, 0, 0, 0};
      for (int i = tid; i < 18944 / 8; i += 256) ((int4*)B1)[i] = zz;   // Apmv [64][296]
    }
    __syncthreads();
    // pri: M=64, N=32, K=160 -> scatter Apmv (B1)
    {
      int nt = wv & 1, mtb = (wv >> 1) * 2;
      f32x4 a0 = {}, a1 = {};
#pragma unroll
      for (int k = 0; k < 160; k += 32) {
        f16x8 bf = *(const f16x8*)(P.wpri + (nt * 16 + lm) * 160 + k + q * 8);
        f16x8 x0 = *(const f16x8*)(B3 + (mtb * 16 + lm) * 168 + k + q * 8);
        f16x8 x1 = *(const f16x8*)(B3 + ((mtb + 1) * 16 + lm) * 168 + k + q * 8);
        a0 = MFMA(x0, bf, a0);
        a1 = MFMA(x1, bf, a1);
      }
      float bb = P.bpri[nt * 16 + lm];
#pragma unroll
      for (int r = 0; r < 4; ++r) {
        scat8_lds(B1, 296, mtb * 16 + q * 4 + r, nt * 16 + lm, fmaxf(a0[r] + bb, 0.f));
        scat8_lds(B1, 296, (mtb + 1) * 16 + q * 4 + r, nt * 16 + lm, fmaxf(a1[r] + bb, 0.f));
      }
    }
    __syncthreads();
    // prim+priv dual: M=64, K=288 -> pm, plv
    {
      f32x4 am[4] = {}, av[4] = {};
      int ch = wv * 16 + lm;
#pragma unroll
      for (int k = 0; k < 288; k += 32) {
        f16x8 bm = *(const f16x8*)(P.wpmv + (long)ch * 288 + k + q * 8);
        f16x8 bv = *(const f16x8*)(P.wpmv + (long)(64 + ch) * 288 + k + q * 8);
#pragma unroll
        for (int mt = 0; mt < 4; ++mt) {
          f16x8 a = *(const f16x8*)(B1 + (mt * 16 + lm) * 296 + k + q * 8);
          am[mt] = MFMA(a, bm, am[mt]);
          av[mt] = MFMA(a, bv, av[mt]);
        }
      }
      float bbm = P.bpm[ch], bbv = P.bpv[ch];
#pragma unroll
      for (int mt = 0; mt < 4; ++mt)
#pragma unroll
        for (int r = 0; r < 4; ++r) {
          int pos = mt * 16 + q * 4 + r;
          P.pm[(long)b * 4096 + ch * 64 + pos] = am[mt][r] + bbm;
          P.plv[(long)b * 4096 + ch * 64 + pos] = softplusf_(av[mt][r] + bbv);
        }
    }
  }
}

// =================== GRU GEMMs: 64x32 wave tiles, wi K-split ===================
// grid (48, 3): z=0 wi k<1536 -> gih0; z=1 wi k>=1536 -> gih1; z=2 wh -> ghh. No bias (gates adds).
__global__ __launch_bounds__(256) void k_gru(const f16* __restrict__ gi,
                                             const f16* __restrict__ wi, const f16* __restrict__ wh,
                                             float* __restrict__ gih0, float* __restrict__ gih1,
                                             float* __restrict__ ghh) {
  int z = blockIdx.y;
  int wv = threadIdx.x >> 6, lane = threadIdx.x & 63, lm = lane & 15, q = lane >> 4;
  int gw = blockIdx.x * 4 + wv;          // 0..191
  int mg = gw & 1, ng = gw >> 1;         // m0 in {0,64}, n0 = ng*32
  const f16* A = (z == 2) ? gi + 2048 : gi;
  const f16* B = (z == 2) ? wh : wi;
  int K = (z == 2) ? 1024 : 1536;
  int k0 = (z == 1) ? 1536 : 0;
  long ldb = (z == 2) ? 1024 : 3072;
  float* out = (z == 0) ? gih0 : (z == 1) ? gih1 : ghh;
  int m0 = mg * 64, n0 = ng * 32;
  f32x4 acc[4][2] = {};
  const f16* Ap = A + (long)(m0 + lm) * 3072 + k0 + q * 8;
  const f16* Bp = B + (long)(n0 + lm) * ldb + k0 + q * 8;
#pragma unroll 2
  for (int k = 0; k < K; k += 32) {
    f16x8 b0 = *(const f16x8*)(Bp + k);
    f16x8 b1 = *(const f16x8*)(Bp + 16 * ldb + k);
#pragma unroll
    for (int i = 0; i < 4; ++i) {
      f16x8 a = *(const f16x8*)(Ap + (long)i * 16 * 3072 + k);
      acc[i][0] = MFMA(a, b0, acc[i][0]);
      acc[i][1] = MFMA(a, b1, acc[i][1]);
    }
  }
#pragma unroll
  for (int i = 0; i < 4; ++i)
#pragma unroll
    for (int j = 0; j < 2; ++j)
#pragma unroll
      for (int r = 0; r < 4; ++r)
        out[(long)(m0 + i * 16 + q * 4 + r) * 3072 + n0 + j * 16 + lm] = acc[i][j][r];
}

extern "C" void kernel_launch(void* const* d_in, const int* in_sizes, int n_in,
                              void* d_out, int out_size, void* d_ws, size_t ws_size,
                              hipStream_t stream) {
  const float* x       = (const float*)d_in[0];
  const float* eps     = (const float*)d_in[1];
  const float* psix1_w = (const float*)d_in[2];
  const float* psix1_b = (const float*)d_in[3];
  const float* psix2_w = (const float*)d_in[4];
  const float* psix2_b = (const float*)d_in[5];
  const float* psiz_w  = (const float*)d_in[6];
  const float* psiz_b  = (const float*)d_in[7];
  const float* enc1_w  = (const float*)d_in[8];
  const float* enc1_b  = (const float*)d_in[9];
  const float* enc2_w  = (const float*)d_in[10];
  const float* enc2_b  = (const float*)d_in[11];
  const float* encm_w  = (const float*)d_in[12];
  const float* encm_b  = (const float*)d_in[13];
  const float* encv_w  = (const float*)d_in[14];
  const float* encv_b  = (const float*)d_in[15];
  const float* pri_w   = (const float*)d_in[16];
  const float* pri_b   = (const float*)d_in[17];
  const float* prim_w  = (const float*)d_in[18];
  const float* prim_b  = (const float*)d_in[19];
  const float* priv_w  = (const float*)d_in[20];
  const float* priv_b  = (const float*)d_in[21];
  const float* dec1_w  = (const float*)d_in[22];
  const float* dec1_b  = (const float*)d_in[23];
  const float* dec2_w  = (const float*)d_in[24];
  const float* dec2_b  = (const float*)d_in[25];
  const float* gru_wi  = (const float*)d_in[26];
  const float* gru_wh  = (const float*)d_in[27];
  const float* gru_bi  = (const float*)d_in[28];
  const float* gru_bh  = (const float*)d_in[29];

  float* out = (float*)d_out;
  float* zm_out  = out + 10616832;
  float* zlv_out = zm_out + 524288;
  float* pm_out  = zlv_out + 524288;
  float* plv_out = pm_out + 524288;

  f16* ws16 = (f16*)d_ws;
  f16* wi_f  = ws16 + OFF_WI;
  f16* wh_f  = ws16 + OFF_WH;
  f16* w_px1 = ws16 + OFF_WPX1;
  f16* w_px2 = ws16 + OFF_WPX2;
  f16* w_e1  = ws16 + OFF_WE1;
  f16* w_e2  = ws16 + OFF_WE2;
  f16* w_mv  = ws16 + OFF_WMV;
  f16* w_pz  = ws16 + OFF_WPZ;
  f16* w_pri = ws16 + OFF_WPRI;
  f16* w_pmv = ws16 + OFF_WPMV;
  f16* w_d1  = ws16 + OFF_WD1;
  f16* gi    = ws16 + OFF_GI;
  float* fws = (float*)(ws16 + OFF_F16_END);
  float* gih0 = fws;                 // 393216
  float* gih1 = gih0 + 393216;       // 393216
  float* ghh  = gih1 + 393216;       // 393216
  float* hG   = ghh + 393216;        // 131072

  k_wpack<<<2048, 256, 0, stream>>>(gru_wi, wi_f, 3072, 3072, 3072);
  k_wpack<<<1024, 256, 0, stream>>>(gru_wh, wh_f, 3072, 1024, 1024);
  k_wpack<<<2, 256, 0, stream>>>(psix1_w, w_px1, 16, 27, 32);
  k_wpack<<<10, 256, 0, stream>>>(psix2_w, w_px2, 16, 144, 160);
  k_wpack<<<36, 256, 0, stream>>>(enc1_w, w_e1, 32, 288, 288);
  k_wpack<<<72, 256, 0, stream>>>(enc2_w, w_e2, 64, 288, 288);
  k_wpack<<<144, 256, 0, stream>>>(encm_w, w_mv, 64, 576, 576);
  k_wpack<<<144, 256, 0, stream>>>(encv_w, w_mv + 64L * 576, 64, 576, 576);
  k_wpack<<<36, 256, 0, stream>>>(psiz_w, w_pz, 16, 576, 576);
  k_wpack<<<20, 256, 0, stream>>>(pri_w, w_pri, 32, 144, 160);
  k_wpack<<<72, 256, 0, stream>>>(prim_w, w_pmv, 64, 288, 288);
  k_wpack<<<72, 256, 0, stream>>>(priv_w, w_pmv + 64L * 288, 64, 288, 288);
  k_wd1<<<36, 256, 0, stream>>>(dec1_w, w_d1);

  for (int t = 0; t < NSTEP; ++t) {
    Params P;
    P.frame = (t < 6) ? x + (long)t * 3072 : out + (long)(t - 1) * 3072;
    P.fstride = (t < 6) ? 86016 : 82944;
    P.eps_t = eps + (long)t * 524288;
    P.wpx1 = w_px1; P.wpx2 = w_px2; P.we1 = w_e1; P.we2 = w_e2;
    P.wmv = w_mv; P.wpz = w_pz; P.wd1 = w_d1; P.wpri = w_pri; P.wpmv = w_pmv;
    P.bpx1 = psix1_b; P.bpx2 = psix2_b; P.be1 = enc1_b; P.be2 = enc2_b;
    P.bm = encm_b; P.bv = encv_b; P.bpz = psiz_b; P.bd1 = dec1_b;
    P.d2w = dec2_w; P.d2b = dec2_b; P.bpri = pri_b; P.bpm = prim_b; P.bpv = priv_b;
    P.gbi = gru_bi; P.gbh = gru_bh;
    P.gih0 = gih0; P.gih1 = gih1; P.ghh = ghh;
    P.hG = hG; P.gi = gi;
    P.out_t = out + (long)t * 3072;
    P.zm = zm_out; P.zlv = zlv_out; P.pm = pm_out; P.plv = plv_out;
    P.t = t; P.last = (t == NSTEP - 1);
    k_step<<<128, 256, 0, stream>>>(P);
    if (t < NSTEP - 1)
      k_gru<<<dim3(48, 3), 256, 0, stream>>>(gi, wi_f, wh_f, gih0, gih1, ghh);
  }
}